// Round 7
// baseline (352.248 us; speedup 1.0000x reference)
//
#include <hip/hip_runtime.h>
#include <hip/hip_bf16.h>

// Problem: B=8, S=4096, D=768
//   y = tanh(x @ W); scores = y . v; w = softmax_S(scores); out = sum_s w * x
constexpr int Bb = 8;
constexpr int Ss = 4096;
constexpr int Dd = 768;
constexpr int Mm = Bb * Ss;      // 32768 rows

constexpr int BM = 64;           // block rows
constexpr int BN = 256;          // block cols (n-split 3)
constexpr int LDS_S = 40;        // LDS row stride in bf16 (80 B): b128 frag reads 2 lanes/bank = free

typedef __bf16 bf16x8 __attribute__((ext_vector_type(8)));
typedef __bf16 bf16x4 __attribute__((ext_vector_type(4)));
typedef float f32x4 __attribute__((ext_vector_type(4)));

__device__ __forceinline__ float fast_tanh(float x) {
    return 1.f - 2.f / (__expf(2.f * x) + 1.f);
}

// ---------------- Kernel 0: W[k][n] fp32 -> Wt[n][k] bf16 (LDS-tiled transpose)
__global__ __launch_bounds__(256) void convW(const float* __restrict__ W,
                                             __bf16* __restrict__ Wt) {
    __shared__ float tile[32][33];
    const int tx = threadIdx.x & 31;
    const int ty = threadIdx.x >> 5;
    const int kb = blockIdx.x * 32;
    const int nb = blockIdx.y * 32;
#pragma unroll
    for (int i = 0; i < 32; i += 8)
        tile[ty + i][tx] = W[(size_t)(kb + ty + i) * Dd + nb + tx];
    __syncthreads();
#pragma unroll
    for (int i = 0; i < 32; i += 8)
        Wt[(size_t)(nb + ty + i) * Dd + kb + tx] = (__bf16)tile[tx][ty + i];
}

// ---------------- Kernel 1: scores[m] += sum_n v[n]*tanh( (x@W)[m][n] )
// 64x256 block tile, 256 thr = 4 waves, wave tile 64x64 (16 MFMA : 8 ds_read).
// All staging via VGPRs (no global_load_lds -> no vmcnt(0) barrier drain, padded
// LDS stride legal). Double-buffered LDS, ONE barrier/kstep. 51 KB LDS +
// VGPR<=170 -> 3 blocks/CU = 3 independent barrier groups.
// grid = (3 nb, 512 mb), nb fastest -> same-m blocks adjacent (x via L3).
__global__ __launch_bounds__(256, 3) void scores_gemm(
    const float* __restrict__ x, const __bf16* __restrict__ Wt,
    const float* __restrict__ v, float* __restrict__ scores) {
    __shared__ __bf16 As[2][BM * LDS_S];   // 2 x 5120 B
    __shared__ __bf16 Bs[2][BN * LDS_S];   // 2 x 20480 B
    __shared__ float ssc[4][BM];           // 1 KB

    const int t = threadIdx.x;
    const int nb = blockIdx.x;             // 0..2
    const int mb = blockIdx.y;             // 0..511
    const int lane = t & 63;
    const int w = t >> 6;                  // wave 0..3 (owns cols w*64..w*64+63)
    const int quad = lane >> 4;
    const int lid = lane & 15;

    // A staging: 2 float4/thread. f = j*256+t -> row = f>>3 (0..63), c4 = f&7
    const int ar0 = t >> 3;                // j=0 row (0..31)
    const int ac4 = t & 7;
    const float* agp = x + (size_t)(mb * BM) * Dd;
    // B staging: 4 uint4/thread. u = j*256+t -> col = u>>2, uu = u&3
    const int bc0 = t >> 2;                // j=0 col (0..63)
    const int buu = t & 3;
    const __bf16* bgp = Wt + (size_t)(nb * BN) * Dd;

    f32x4 acc[4][4];
#pragma unroll
    for (int i = 0; i < 4; ++i)
#pragma unroll
        for (int j = 0; j < 4; ++j) acc[i][j] = (f32x4){0.f, 0.f, 0.f, 0.f};

    float4 areg[2];
    uint4 breg[4];

    auto issue_loads = [&](int kb) {
#pragma unroll
        for (int j = 0; j < 2; ++j)
            areg[j] = *(const float4*)(agp + (size_t)(ar0 + j * 32) * Dd + kb * 32 + ac4 * 4);
#pragma unroll
        for (int j = 0; j < 4; ++j)
            breg[j] = *(const uint4*)(bgp + (size_t)(bc0 + j * 64) * Dd + kb * 32 + buu * 8);
    };
    auto write_lds = [&](int p) {
#pragma unroll
        for (int j = 0; j < 2; ++j) {
            bf16x4 pa;
            pa[0] = (__bf16)areg[j].x; pa[1] = (__bf16)areg[j].y;
            pa[2] = (__bf16)areg[j].z; pa[3] = (__bf16)areg[j].w;
            *(bf16x4*)(&As[p][(ar0 + j * 32) * LDS_S + ac4 * 4]) = pa;
        }
#pragma unroll
        for (int j = 0; j < 4; ++j)
            *(uint4*)(&Bs[p][(bc0 + j * 64) * LDS_S + buu * 8]) = breg[j];
    };

    // prologue: stage kstep 0 into buf 0
    issue_loads(0);
    write_lds(0);

    for (int kb = 0; kb < 24; ++kb) {
        const int p = kb & 1;
        __syncthreads();                   // buf p ready; buf 1-p free
        if (kb < 23) issue_loads(kb + 1);  // global loads land during MFMA phase

        bf16x8 af[4], bfr[4];
#pragma unroll
        for (int tm = 0; tm < 4; ++tm)
            af[tm] = *(const bf16x8*)(&As[p][(tm * 16 + lid) * LDS_S + quad * 8]);
#pragma unroll
        for (int tn = 0; tn < 4; ++tn)
            bfr[tn] = *(const bf16x8*)(&Bs[p][(w * 64 + tn * 16 + lid) * LDS_S + quad * 8]);

#pragma unroll
        for (int tm = 0; tm < 4; ++tm)
#pragma unroll
            for (int tn = 0; tn < 4; ++tn)
                acc[tm][tn] = __builtin_amdgcn_mfma_f32_16x16x32_bf16(af[tm], bfr[tn], acc[tm][tn], 0, 0, 0);

        if (kb < 23) write_lds(1 - p);     // convert + LDS write after MFMAs
    }

    // epilogue: fold tanh*v over this block's 256 cols, reduce to 64 row scores
    float vv[4];
#pragma unroll
    for (int tn = 0; tn < 4; ++tn)
        vv[tn] = v[nb * BN + w * 64 + tn * 16 + lid];

#pragma unroll
    for (int tm = 0; tm < 4; ++tm)
#pragma unroll
        for (int r = 0; r < 4; ++r) {
            float s = 0.f;
#pragma unroll
            for (int tn = 0; tn < 4; ++tn) s += vv[tn] * fast_tanh(acc[tm][tn][r]);
            // C layout: col=lid, row=quad*4+r
            s += __shfl_xor(s, 1);
            s += __shfl_xor(s, 2);
            s += __shfl_xor(s, 4);
            s += __shfl_xor(s, 8);
            if (lid == 0) ssc[w][tm * 16 + quad * 4 + r] = s;
        }
    __syncthreads();
    if (t < BM) {
        float s = ssc[0][t] + ssc[1][t] + ssc[2][t] + ssc[3][t];
        atomicAdd(&scores[mb * BM + t], s);
    }
}

// ---------------- Kernel 2: fused softmax + partial pool (no atomics)
// grid = (128 chunks, B), 192 thr (3 waves). Softmax stats via EXACT per-wave
// shfl_xor reductions + 3-way cross-wave combine (the round-6 bug was a
// power-of-two LDS tree on a 192-thread block dropping one partial).
__global__ __launch_bounds__(192) void pool1(const float* __restrict__ x,
                                             const float* __restrict__ scores,
                                             float* __restrict__ partial) {
    const int b = blockIdx.y;
    const int c = blockIdx.x;            // 128 chunks x 32 rows
    const int t = threadIdx.x;           // owns float4 at d = t*4
    const int wv = t >> 6;
    const int ln = t & 63;
    const float* srow = scores + (size_t)b * Ss;
    __shared__ float redm[3], reds[3];

    float mx = -1e30f;
    for (int i = t; i < Ss; i += 192) mx = fmaxf(mx, srow[i]);
#pragma unroll
    for (int o = 32; o > 0; o >>= 1) mx = fmaxf(mx, __shfl_xor(mx, o));
    if (ln == 0) redm[wv] = mx;
    __syncthreads();
    mx = fmaxf(redm[0], fmaxf(redm[1], redm[2]));

    float sum = 0.f;
    for (int i = t; i < Ss; i += 192) sum += __expf(srow[i] - mx);
#pragma unroll
    for (int o = 32; o > 0; o >>= 1) sum += __shfl_xor(sum, o);
    if (ln == 0) reds[wv] = sum;
    __syncthreads();
    const float inv = 1.f / (reds[0] + reds[1] + reds[2]);

    const float* base = x + ((size_t)b * Ss + c * 32) * Dd;
    float4 acc = make_float4(0.f, 0.f, 0.f, 0.f);
#pragma unroll 8
    for (int i = 0; i < 32; ++i) {
        const float ww = __expf(srow[c * 32 + i] - mx) * inv;
        const float4 xv = *(const float4*)(base + (size_t)i * Dd + t * 4);
        acc.x += ww * xv.x;
        acc.y += ww * xv.y;
        acc.z += ww * xv.z;
        acc.w += ww * xv.w;
    }
    *(float4*)(partial + ((size_t)(b * 128 + c)) * Dd + t * 4) = acc;
}

// ---------------- Kernel 3: out[b][d] = sum_c partial[b][c][d]
__global__ __launch_bounds__(768) void pool2(const float* __restrict__ partial,
                                             float* __restrict__ out) {
    const int b = blockIdx.x;
    const int d = threadIdx.x;           // 0..767
    float s = 0.f;
#pragma unroll 8
    for (int c = 0; c < 128; ++c) s += partial[((size_t)(b * 128 + c)) * Dd + d];
    out[(size_t)b * Dd + d] = s;
}

extern "C" void kernel_launch(void* const* d_in, const int* in_sizes, int n_in,
                              void* d_out, int out_size, void* d_ws, size_t ws_size,
                              hipStream_t stream) {
    (void)in_sizes; (void)n_in; (void)ws_size; (void)out_size;
    const float* x = (const float*)d_in[0];
    const float* v = (const float*)d_in[1];
    const float* W = (const float*)d_in[2];

    char* ws = (char*)d_ws;
    __bf16* Wt = (__bf16*)ws;                             // 1,179,648 B
    float* scores = (float*)(ws + 1179648);               //   131,072 B
    float* partial = (float*)(ws + 1179648 + 131072);     // 3,145,728 B (8*128*768 f32)

    hipMemsetAsync(scores, 0, Mm * sizeof(float), stream);

    convW<<<dim3(Dd / 32, Dd / 32), 256, 0, stream>>>(W, Wt);
    scores_gemm<<<dim3(3, Mm / BM), 256, 0, stream>>>(x, Wt, v, scores);
    pool1<<<dim3(128, Bb), 192, 0, stream>>>(x, scores, partial);
    pool2<<<dim3(Bb), 768, 0, stream>>>(partial, (float*)d_out);
}

// Round 8
// 348.626 us; speedup vs baseline: 1.0104x; 1.0104x over previous
//
#include <hip/hip_runtime.h>
#include <hip/hip_bf16.h>

// Problem: B=8, S=4096, D=768
//   y = tanh(x @ W); scores = y . v; w = softmax_S(scores); out = sum_s w * x
constexpr int Bb = 8;
constexpr int Ss = 4096;
constexpr int Dd = 768;
constexpr int Mm = Bb * Ss;      // 32768 rows

constexpr int BM = 64;           // block rows
constexpr int BN = 256;          // block cols (n-split 3)
constexpr int LDS_S = 40;        // LDS row stride in bf16 (80 B): b128 frag reads 2 lanes/bank = free

typedef __bf16 bf16x8 __attribute__((ext_vector_type(8)));
typedef __bf16 bf16x4 __attribute__((ext_vector_type(4)));
typedef float f32x4 __attribute__((ext_vector_type(4)));

__device__ __forceinline__ float fast_tanh(float x) {
    return 1.f - 2.f / (__expf(2.f * x) + 1.f);
}

// ---------------- Kernel 0: W[k][n] fp32 -> Wt[n][k] bf16 (LDS-tiled transpose)
__global__ __launch_bounds__(256) void convW(const float* __restrict__ W,
                                             __bf16* __restrict__ Wt) {
    __shared__ float tile[32][33];
    const int tx = threadIdx.x & 31;
    const int ty = threadIdx.x >> 5;
    const int kb = blockIdx.x * 32;
    const int nb = blockIdx.y * 32;
#pragma unroll
    for (int i = 0; i < 32; i += 8)
        tile[ty + i][tx] = W[(size_t)(kb + ty + i) * Dd + nb + tx];
    __syncthreads();
#pragma unroll
    for (int i = 0; i < 32; i += 8)
        Wt[(size_t)(nb + ty + i) * Dd + kb + tx] = (__bf16)tile[tx][ty + i];
}

// ---------------- Kernel 1: scores[m] += sum_n v[n]*tanh( (x@W)[m][n] )
// 64x256 block tile, 256 thr = 4 waves, wave tile 64x64 (16 MFMA : 8 ds_read).
// All staging via VGPRs. Double-buffered LDS, ONE barrier/kstep.
// ROUND 8 FIX: launch_bounds min-waves 3 -> 2. The (256,3) cap forced arch
// VGPRs to 72 and spilled the 24 staging regs each kstep (~200 MB scratch
// writes = round 7's WRITE_SIZE). Budget 256 lets ~150 live regs stay
// resident; expected occupancy still ~3 blocks/CU from natural allocation.
__global__ __launch_bounds__(256, 2) void scores_gemm(
    const float* __restrict__ x, const __bf16* __restrict__ Wt,
    const float* __restrict__ v, float* __restrict__ scores) {
    __shared__ __bf16 As[2][BM * LDS_S];   // 2 x 5120 B
    __shared__ __bf16 Bs[2][BN * LDS_S];   // 2 x 20480 B
    __shared__ float ssc[4][BM];           // 1 KB

    const int t = threadIdx.x;
    const int nb = blockIdx.x;             // 0..2
    const int mb = blockIdx.y;             // 0..511
    const int lane = t & 63;
    const int w = t >> 6;                  // wave 0..3 (owns cols w*64..w*64+63)
    const int quad = lane >> 4;
    const int lid = lane & 15;

    // A staging: 2 float4/thread. f = j*256+t -> row = f>>3 (0..63), c4 = f&7
    const int ar0 = t >> 3;                // j=0 row (0..31)
    const int ac4 = t & 7;
    const float* agp = x + (size_t)(mb * BM) * Dd;
    // B staging: 4 uint4/thread. u = j*256+t -> col = u>>2, uu = u&3
    const int bc0 = t >> 2;                // j=0 col (0..63)
    const int buu = t & 3;
    const __bf16* bgp = Wt + (size_t)(nb * BN) * Dd;

    f32x4 acc[4][4];
#pragma unroll
    for (int i = 0; i < 4; ++i)
#pragma unroll
        for (int j = 0; j < 4; ++j) acc[i][j] = (f32x4){0.f, 0.f, 0.f, 0.f};

    float4 areg[2];
    uint4 breg[4];

    auto issue_loads = [&](int kb) {
#pragma unroll
        for (int j = 0; j < 2; ++j)
            areg[j] = *(const float4*)(agp + (size_t)(ar0 + j * 32) * Dd + kb * 32 + ac4 * 4);
#pragma unroll
        for (int j = 0; j < 4; ++j)
            breg[j] = *(const uint4*)(bgp + (size_t)(bc0 + j * 64) * Dd + kb * 32 + buu * 8);
    };
    auto write_lds = [&](int p) {
#pragma unroll
        for (int j = 0; j < 2; ++j) {
            bf16x4 pa;
            pa[0] = (__bf16)areg[j].x; pa[1] = (__bf16)areg[j].y;
            pa[2] = (__bf16)areg[j].z; pa[3] = (__bf16)areg[j].w;
            *(bf16x4*)(&As[p][(ar0 + j * 32) * LDS_S + ac4 * 4]) = pa;
        }
#pragma unroll
        for (int j = 0; j < 4; ++j)
            *(uint4*)(&Bs[p][(bc0 + j * 64) * LDS_S + buu * 8]) = breg[j];
    };

    // prologue: stage kstep 0 into buf 0
    issue_loads(0);
    write_lds(0);

    for (int kb = 0; kb < 24; ++kb) {
        const int p = kb & 1;
        __syncthreads();                   // buf p ready; buf 1-p free
        if (kb < 23) issue_loads(kb + 1);  // global loads land during MFMA phase

        bf16x8 af[4], bfr[4];
#pragma unroll
        for (int tm = 0; tm < 4; ++tm)
            af[tm] = *(const bf16x8*)(&As[p][(tm * 16 + lid) * LDS_S + quad * 8]);
#pragma unroll
        for (int tn = 0; tn < 4; ++tn)
            bfr[tn] = *(const bf16x8*)(&Bs[p][(w * 64 + tn * 16 + lid) * LDS_S + quad * 8]);

#pragma unroll
        for (int tm = 0; tm < 4; ++tm)
#pragma unroll
            for (int tn = 0; tn < 4; ++tn)
                acc[tm][tn] = __builtin_amdgcn_mfma_f32_16x16x32_bf16(af[tm], bfr[tn], acc[tm][tn], 0, 0, 0);

        if (kb < 23) write_lds(1 - p);     // convert + LDS write after MFMAs
    }

    // epilogue: fold tanh*v over this block's 256 cols, reduce to 64 row scores
    float vv[4];
#pragma unroll
    for (int tn = 0; tn < 4; ++tn)
        vv[tn] = v[nb * BN + w * 64 + tn * 16 + lid];

#pragma unroll
    for (int tm = 0; tm < 4; ++tm)
#pragma unroll
        for (int r = 0; r < 4; ++r) {
            float s = 0.f;
#pragma unroll
            for (int tn = 0; tn < 4; ++tn) s += vv[tn] * fast_tanh(acc[tm][tn][r]);
            // C layout: col=lid, row=quad*4+r
            s += __shfl_xor(s, 1);
            s += __shfl_xor(s, 2);
            s += __shfl_xor(s, 4);
            s += __shfl_xor(s, 8);
            if (lid == 0) ssc[w][tm * 16 + quad * 4 + r] = s;
        }
    __syncthreads();
    if (t < BM) {
        float s = ssc[0][t] + ssc[1][t] + ssc[2][t] + ssc[3][t];
        atomicAdd(&scores[mb * BM + t], s);
    }
}

// ---------------- Kernel 2: fused softmax + partial pool (no atomics)
// grid = (128 chunks, B), 192 thr (3 waves). Exact per-wave shfl reductions +
// 3-way cross-wave combine.
__global__ __launch_bounds__(192) void pool1(const float* __restrict__ x,
                                             const float* __restrict__ scores,
                                             float* __restrict__ partial) {
    const int b = blockIdx.y;
    const int c = blockIdx.x;            // 128 chunks x 32 rows
    const int t = threadIdx.x;           // owns float4 at d = t*4
    const int wv = t >> 6;
    const int ln = t & 63;
    const float* srow = scores + (size_t)b * Ss;
    __shared__ float redm[3], reds[3];

    float mx = -1e30f;
    for (int i = t; i < Ss; i += 192) mx = fmaxf(mx, srow[i]);
#pragma unroll
    for (int o = 32; o > 0; o >>= 1) mx = fmaxf(mx, __shfl_xor(mx, o));
    if (ln == 0) redm[wv] = mx;
    __syncthreads();
    mx = fmaxf(redm[0], fmaxf(redm[1], redm[2]));

    float sum = 0.f;
    for (int i = t; i < Ss; i += 192) sum += __expf(srow[i] - mx);
#pragma unroll
    for (int o = 32; o > 0; o >>= 1) sum += __shfl_xor(sum, o);
    if (ln == 0) reds[wv] = sum;
    __syncthreads();
    const float inv = 1.f / (reds[0] + reds[1] + reds[2]);

    const float* base = x + ((size_t)b * Ss + c * 32) * Dd;
    float4 acc = make_float4(0.f, 0.f, 0.f, 0.f);
#pragma unroll 8
    for (int i = 0; i < 32; ++i) {
        const float ww = __expf(srow[c * 32 + i] - mx) * inv;
        const float4 xv = *(const float4*)(base + (size_t)i * Dd + t * 4);
        acc.x += ww * xv.x;
        acc.y += ww * xv.y;
        acc.z += ww * xv.z;
        acc.w += ww * xv.w;
    }
    *(float4*)(partial + ((size_t)(b * 128 + c)) * Dd + t * 4) = acc;
}

// ---------------- Kernel 3: out[b][d] = sum_c partial[b][c][d]
__global__ __launch_bounds__(768) void pool2(const float* __restrict__ partial,
                                             float* __restrict__ out) {
    const int b = blockIdx.x;
    const int d = threadIdx.x;           // 0..767
    float s = 0.f;
#pragma unroll 8
    for (int c = 0; c < 128; ++c) s += partial[((size_t)(b * 128 + c)) * Dd + d];
    out[(size_t)b * Dd + d] = s;
}

extern "C" void kernel_launch(void* const* d_in, const int* in_sizes, int n_in,
                              void* d_out, int out_size, void* d_ws, size_t ws_size,
                              hipStream_t stream) {
    (void)in_sizes; (void)n_in; (void)ws_size; (void)out_size;
    const float* x = (const float*)d_in[0];
    const float* v = (const float*)d_in[1];
    const float* W = (const float*)d_in[2];

    char* ws = (char*)d_ws;
    __bf16* Wt = (__bf16*)ws;                             // 1,179,648 B
    float* scores = (float*)(ws + 1179648);               //   131,072 B
    float* partial = (float*)(ws + 1179648 + 131072);     // 3,145,728 B (8*128*768 f32)

    hipMemsetAsync(scores, 0, Mm * sizeof(float), stream);

    convW<<<dim3(Dd / 32, Dd / 32), 256, 0, stream>>>(W, Wt);
    scores_gemm<<<dim3(3, Mm / BM), 256, 0, stream>>>(x, Wt, v, scores);
    pool1<<<dim3(128, Bb), 192, 0, stream>>>(x, scores, partial);
    pool2<<<dim3(Bb), 768, 0, stream>>>(partial, (float*)d_out);
}